// Round 4
// baseline (604.190 us; speedup 1.0000x reference)
//
#include <hip/hip_runtime.h>

#define N_PTS 16384
#define DIMS  128
#define NQ    16384
#define NV    64
#define KTOT  384   // 3 fp16 products: a1b1 + a1b2 + a2b1 (a2b2 dropped, ~3e-5 abs)
#define BK    64
#define BM    128
#define BN    128

typedef __attribute__((ext_vector_type(8))) _Float16 half8;
typedef __attribute__((ext_vector_type(4))) _Float16 half4;
typedef __attribute__((ext_vector_type(4))) float    f32x4;

// ---------------- split queries: [h1 | h1 | h2] ----------------
__global__ __launch_bounds__(256) void split_q(const float* __restrict__ in,
                                               _Float16* __restrict__ out) {
    int t = blockIdx.x * 256 + threadIdx.x;
    int idx4 = t * 4;
    int r = idx4 >> 7, c = idx4 & 127;
    float4 x = *(const float4*)(in + idx4);
    float xs[4] = {x.x, x.y, x.z, x.w};
    half4 h1, h2;
#pragma unroll
    for (int j = 0; j < 4; ++j) {
        _Float16 a = (_Float16)xs[j];
        h1[j] = a;
        h2[j] = (_Float16)(xs[j] - (float)a);
    }
    _Float16* o = out + (size_t)r * KTOT + c;
    *(half4*)o = h1; *(half4*)(o + 128) = h1; *(half4*)(o + 256) = h2;
}

// ---------------- split points: [h1 | h2 | h1], fused p_sq ----------------
__global__ __launch_bounds__(256) void split_p(const float* __restrict__ in,
                                               _Float16* __restrict__ out,
                                               float* __restrict__ p_sq) {
    int t = blockIdx.x * 256 + threadIdx.x;
    int idx4 = t * 4;                 // 32 threads per 128-float row
    int r = idx4 >> 7, c = idx4 & 127;
    float4 x = *(const float4*)(in + idx4);
    float xs[4] = {x.x, x.y, x.z, x.w};
    half4 h1, h2;
    float s = 0.f;
#pragma unroll
    for (int j = 0; j < 4; ++j) {
        _Float16 a = (_Float16)xs[j];
        h1[j] = a;
        h2[j] = (_Float16)(xs[j] - (float)a);
        s += xs[j] * xs[j];
    }
    _Float16* o = out + (size_t)r * KTOT + c;
    *(half4*)o = h1; *(half4*)(o + 128) = h2; *(half4*)(o + 256) = h1;
#pragma unroll
    for (int off = 1; off < 32; off <<= 1) s += __shfl_xor(s, off, 64);
    if ((threadIdx.x & 31) == 0) p_sq[r] = s;
}

__device__ __forceinline__ unsigned int f2sortable(float f) {
    unsigned int b = __float_as_uint(f);
    return (b & 0x80000000u) ? ~b : (b | 0x80000000u);
}

__device__ __forceinline__ void gload16(const void* g, void* l) {
    __builtin_amdgcn_global_load_lds((const __attribute__((address_space(1))) void*)g,
                                     (__attribute__((address_space(3))) void*)l, 16, 0, 0);
}

// -------- main: m97-structure 128x128 tile, 4 waves of 64x64, 16x16x32 fp16 --------
__global__ __launch_bounds__(256) void nn_mfma(const _Float16* __restrict__ A,   // [NQ][KTOT]
                                               const _Float16* __restrict__ B,   // [N_PTS][KTOT]
                                               const float* __restrict__ p_sq,
                                               unsigned long long* __restrict__ keys) {
    __shared__ _Float16 As[BM * BK];   // 16 KB
    __shared__ _Float16 Bs[BN * BK];   // 16 KB

    // 128x128 tiles; 8x8 supertile swizzle for L2 locality
    int bid = blockIdx.x;
    int g  = bid >> 6;                  // 0..255
    int gm = g >> 4, gn = g & 15;       // 16 x 16 groups
    int lm = (bid >> 3) & 7, ln = bid & 7;
    int mtile = gm * 8 + lm;            // 0..127
    int ntile = gn * 8 + ln;            // 0..127

    const int tid = threadIdx.x;
    const int w   = tid >> 6;           // wave 0..3
    const int l   = tid & 63;
    const int wq  = w >> 1;             // wave quadrant: rows wq*64, cols wp*64
    const int wp  = w & 1;
    const int q16 = l >> 4;             // MFMA quad
    const int c16 = l & 15;             // MFMA row/col-in-frag

    const int srow = l >> 3;                    // staging row-in-8
    const int gch  = (l & 7) ^ ((l >> 3) & 7);  // swizzled global chunk for this lane
    const size_t arow0 = (size_t)mtile * BM;
    const size_t brow0 = (size_t)ntile * BN;

    f32x4 acc[4][4] = {};

    for (int kk = 0; kk < KTOT; kk += BK) {
        __syncthreads();
        // stage A and B: 128 rows x 64 fp16 each; wave w covers rows w*32..+32, 4 issues each
#pragma unroll
        for (int i = 0; i < 4; ++i) {
            int r = w * 32 + i * 8 + srow;
            gload16(A + (arow0 + r) * KTOT + kk + gch * 8, As + (size_t)(w * 32 + i * 8) * BK);
            gload16(B + (brow0 + r) * KTOT + kk + gch * 8, Bs + (size_t)(w * 32 + i * 8) * BK);
        }
        __syncthreads();

#pragma unroll
        for (int ks = 0; ks < 2; ++ks) {        // 2 MFMA-K steps of 32
            int ch   = ks * 4 + q16;            // 16B chunk within row
            int slot = ch ^ (c16 & 7);          // bank-balanced (2-way = free)
            half8 a[4], b[4];
#pragma unroll
            for (int mi = 0; mi < 4; ++mi)
                a[mi] = *(const half8*)(As + (size_t)(wq * 64 + mi * 16 + c16) * BK + slot * 8);
#pragma unroll
            for (int ni = 0; ni < 4; ++ni)
                b[ni] = *(const half8*)(Bs + (size_t)(wp * 64 + ni * 16 + c16) * BK + slot * 8);
#pragma unroll
            for (int mi = 0; mi < 4; ++mi)
#pragma unroll
                for (int ni = 0; ni < 4; ++ni)
                    acc[mi][ni] = __builtin_amdgcn_mfma_f32_16x16x32_f16(a[mi], b[ni], acc[mi][ni], 0, 0, 0);
        }
    }

    // ---- epilogue: score = p_sq - 2*dot; 16x16 C/D: col=lane&15, row=quad*4+reg ----
    float psq[4];
#pragma unroll
    for (int ni = 0; ni < 4; ++ni)
        psq[ni] = p_sq[ntile * BN + wp * 64 + ni * 16 + c16];

#pragma unroll
    for (int mi = 0; mi < 4; ++mi)
#pragma unroll
        for (int reg = 0; reg < 4; ++reg) {
            int row = mtile * BM + wq * 64 + mi * 16 + q16 * 4 + reg;
            float best = 0.f; int bidx = 0;
#pragma unroll
            for (int ni = 0; ni < 4; ++ni) {
                float s   = psq[ni] - 2.0f * acc[mi][ni][reg];
                int   idx = ntile * BN + wp * 64 + ni * 16 + c16;
                if (ni == 0 || s < best) { best = s; bidx = idx; }   // ni asc => idx asc
            }
#pragma unroll
            for (int off = 1; off < 16; off <<= 1) {                  // 16-lane butterfly (cols)
                float ov = __shfl_xor(best, off, 64);
                int   oi = __shfl_xor(bidx, off, 64);
                if (ov < best || (ov == best && oi < bidx)) { best = ov; bidx = oi; }
            }
            if (c16 == 0) {
                unsigned long long key =
                    ((unsigned long long)f2sortable(best) << 32) | (unsigned int)bidx;
                atomicMin(&keys[row], key);
            }
        }
}

// ---------------- gather: out[q] = values[key[q] & 0xffffffff] ----------------
__global__ __launch_bounds__(256) void gather_kernel(const unsigned long long* __restrict__ keys,
                                                     const float* __restrict__ values,
                                                     float* __restrict__ out) {
    int tid = threadIdx.x;
    int q = blockIdx.x * 16 + (tid >> 4);
    int c = tid & 15;
    int idx = (int)(keys[q] & 0xFFFFFFFFull);
    const float4* src = (const float4*)(values + (size_t)idx * NV);
    float4*       dst = (float4*)(out + (size_t)q * NV);
    dst[c] = src[c];
}

// ================= fallback (round-1 fp32 LDS kernel) =================
#define QT 64
#define PT 64
#define LSTRIDE 132
__global__ __launch_bounds__(256, 2) void nn_kernel(const float* __restrict__ points,
                                                    const float* __restrict__ values,
                                                    const float* __restrict__ pointsq,
                                                    const float* __restrict__ p_sq,
                                                    float* __restrict__ out) {
    __shared__ float lq[QT * LSTRIDE];
    __shared__ float lp[PT * LSTRIDE];
    __shared__ float lps[PT];
    __shared__ float red_val[QT][16];
    __shared__ int   red_idx[QT][16];
    __shared__ int   nn_idx[QT];

    const int tid = threadIdx.x;
    const int tx = tid & 15, ty = tid >> 4;
    const int qbase = blockIdx.x * QT;
    {
        int ql = tid >> 2, quad = tid & 3;
        const float4* src = (const float4*)(pointsq + (size_t)(qbase + ql) * DIMS);
#pragma unroll
        for (int j = 0; j < 8; ++j)
            *(float4*)(lq + ql * LSTRIDE + (quad + 4 * j) * 4) = src[quad + 4 * j];
    }
    float minv[4]; int mini[4];
#pragma unroll
    for (int qi = 0; qi < 4; ++qi) { minv[qi] = 3.4e38f; mini[qi] = 0; }
    for (int tile = 0; tile < N_PTS / PT; ++tile) {
        __syncthreads();
        {
            int pl = tid >> 2, quad = tid & 3;
            const float4* src = (const float4*)(points + (size_t)(tile * PT + pl) * DIMS);
#pragma unroll
            for (int j = 0; j < 8; ++j)
                *(float4*)(lp + pl * LSTRIDE + (quad + 4 * j) * 4) = src[quad + 4 * j];
            if (tid < PT) lps[tid] = p_sq[tile * PT + tid];
        }
        __syncthreads();
        float accl[4][4];
#pragma unroll
        for (int qi = 0; qi < 4; ++qi)
#pragma unroll
            for (int pi = 0; pi < 4; ++pi) accl[qi][pi] = 0.f;
        for (int kc = 0; kc < DIMS / 4; ++kc) {
            float4 aq[4], ap[4];
#pragma unroll
            for (int qi = 0; qi < 4; ++qi) aq[qi] = *(const float4*)(lq + (ty + 16 * qi) * LSTRIDE + kc * 4);
#pragma unroll
            for (int pi = 0; pi < 4; ++pi) ap[pi] = *(const float4*)(lp + (tx + 16 * pi) * LSTRIDE + kc * 4);
#pragma unroll
            for (int qi = 0; qi < 4; ++qi)
#pragma unroll
                for (int pi = 0; pi < 4; ++pi) {
                    accl[qi][pi] += aq[qi].x * ap[pi].x; accl[qi][pi] += aq[qi].y * ap[pi].y;
                    accl[qi][pi] += aq[qi].z * ap[pi].z; accl[qi][pi] += aq[qi].w * ap[pi].w;
                }
        }
#pragma unroll
        for (int qi = 0; qi < 4; ++qi)
#pragma unroll
            for (int pi = 0; pi < 4; ++pi) {
                float score = lps[tx + 16 * pi] - 2.f * accl[qi][pi];
                int idx = tile * PT + tx + 16 * pi;
                if (score < minv[qi]) { minv[qi] = score; mini[qi] = idx; }
            }
    }
    __syncthreads();
#pragma unroll
    for (int qi = 0; qi < 4; ++qi) { red_val[ty + 16 * qi][tx] = minv[qi]; red_idx[ty + 16 * qi][tx] = mini[qi]; }
    __syncthreads();
    if (tid < QT) {
        float bv = red_val[tid][0]; int bi = red_idx[tid][0];
#pragma unroll
        for (int t = 1; t < 16; ++t) {
            float v = red_val[tid][t]; int i = red_idx[tid][t];
            if (v < bv || (v == bv && i < bi)) { bv = v; bi = i; }
        }
        nn_idx[tid] = bi;
    }
    __syncthreads();
    {
        int ql = tid >> 2, quad = tid & 3;
        const float4* src = (const float4*)(values + (size_t)nn_idx[ql] * NV);
        float4* dst = (float4*)(out + (size_t)(qbase + ql) * NV);
#pragma unroll
        for (int j = 0; j < 4; ++j) dst[quad * 4 + j] = src[quad * 4 + j];
    }
}

__global__ __launch_bounds__(256) void psq_kernel(const float* __restrict__ points,
                                                  float* __restrict__ p_sq) {
    int row  = blockIdx.x * 4 + (threadIdx.x >> 6);
    int lane = threadIdx.x & 63;
    float2 v = *(const float2*)(points + row * DIMS + lane * 2);
    float s = v.x * v.x + v.y * v.y;
#pragma unroll
    for (int off = 32; off > 0; off >>= 1) s += __shfl_xor(s, off, 64);
    if (lane == 0) p_sq[row] = s;
}

extern "C" void kernel_launch(void* const* d_in, const int* in_sizes, int n_in,
                              void* d_out, int out_size, void* d_ws, size_t ws_size,
                              hipStream_t stream) {
    const float* points  = (const float*)d_in[0];
    const float* values  = (const float*)d_in[1];
    const float* pointsq = (const float*)d_in[2];
    float*       out     = (float*)d_out;

    // ws layout: keys (128 KB) | p_sq (64 KB) | A' (12 MB) | B' (12 MB)
    const size_t OFF_KEYS = 0;
    const size_t OFF_PSQ  = 131072;
    const size_t OFF_A    = 196608;
    const size_t OFF_B    = OFF_A + (size_t)NQ * KTOT * 2;
    const size_t NEEDED   = OFF_B + (size_t)N_PTS * KTOT * 2;

    if (ws_size >= NEEDED) {
        unsigned long long* keys = (unsigned long long*)((char*)d_ws + OFF_KEYS);
        float*    p_sq = (float*)((char*)d_ws + OFF_PSQ);
        _Float16* Aq   = (_Float16*)((char*)d_ws + OFF_A);
        _Float16* Bp   = (_Float16*)((char*)d_ws + OFF_B);

        hipMemsetAsync(keys, 0xFF, (size_t)NQ * 8, stream);
        split_q<<<NQ * DIMS / 1024, 256, 0, stream>>>(pointsq, Aq);
        split_p<<<N_PTS * DIMS / 1024, 256, 0, stream>>>(points, Bp, p_sq);
        nn_mfma<<<(NQ / BM) * (N_PTS / BN), 256, 0, stream>>>(Aq, Bp, p_sq, keys);
        gather_kernel<<<NQ / 16, 256, 0, stream>>>(keys, values, out);
    } else {
        float* p_sq = (float*)d_ws;
        psq_kernel<<<N_PTS / 4, 256, 0, stream>>>(points, p_sq);
        nn_kernel<<<NQ / QT, 256, 0, stream>>>(points, values, pointsq, p_sq, out);
    }
}

// Round 5
// 572.523 us; speedup vs baseline: 1.0553x; 1.0553x over previous
//
#include <hip/hip_runtime.h>

#define N_PTS 16384
#define DIMS  128
#define NQ    16384
#define NV    64
#define KTOT  384   // 3 fp16 products: a1b1 + a1b2 + a2b1 (a2b2 dropped, ~3e-5 abs)
#define BK    64
#define BM    128
#define BN    128
#define CHUNK_NT 16            // ntiles per block
#define CHUNK_N  (BN * CHUNK_NT)   // 2048 points per block
#define NCHUNK   (N_PTS / CHUNK_N) // 8

typedef __attribute__((ext_vector_type(8))) _Float16 half8;
typedef __attribute__((ext_vector_type(4))) _Float16 half4;
typedef __attribute__((ext_vector_type(4))) float    f32x4;

// ---------------- split queries: [h1 | h1 | h2] ----------------
__global__ __launch_bounds__(256) void split_q(const float* __restrict__ in,
                                               _Float16* __restrict__ out) {
    int t = blockIdx.x * 256 + threadIdx.x;
    int idx4 = t * 4;
    int r = idx4 >> 7, c = idx4 & 127;
    float4 x = *(const float4*)(in + idx4);
    float xs[4] = {x.x, x.y, x.z, x.w};
    half4 h1, h2;
#pragma unroll
    for (int j = 0; j < 4; ++j) {
        _Float16 a = (_Float16)xs[j];
        h1[j] = a;
        h2[j] = (_Float16)(xs[j] - (float)a);
    }
    _Float16* o = out + (size_t)r * KTOT + c;
    *(half4*)o = h1; *(half4*)(o + 128) = h1; *(half4*)(o + 256) = h2;
}

// ---------------- split points: [h1 | h2 | h1], fused p_sq ----------------
__global__ __launch_bounds__(256) void split_p(const float* __restrict__ in,
                                               _Float16* __restrict__ out,
                                               float* __restrict__ p_sq) {
    int t = blockIdx.x * 256 + threadIdx.x;
    int idx4 = t * 4;                 // 32 threads per 128-float row
    int r = idx4 >> 7, c = idx4 & 127;
    float4 x = *(const float4*)(in + idx4);
    float xs[4] = {x.x, x.y, x.z, x.w};
    half4 h1, h2;
    float s = 0.f;
#pragma unroll
    for (int j = 0; j < 4; ++j) {
        _Float16 a = (_Float16)xs[j];
        h1[j] = a;
        h2[j] = (_Float16)(xs[j] - (float)a);
        s += xs[j] * xs[j];
    }
    _Float16* o = out + (size_t)r * KTOT + c;
    *(half4*)o = h1; *(half4*)(o + 128) = h2; *(half4*)(o + 256) = h1;
#pragma unroll
    for (int off = 1; off < 32; off <<= 1) s += __shfl_xor(s, off, 64);
    if ((threadIdx.x & 31) == 0) p_sq[r] = s;
}

__device__ __forceinline__ unsigned int f2sortable(float f) {
    unsigned int b = __float_as_uint(f);
    return (b & 0x80000000u) ? ~b : (b | 0x80000000u);
}

__device__ __forceinline__ void gload16(const void* g, void* l) {
    __builtin_amdgcn_global_load_lds((const __attribute__((address_space(1))) void*)g,
                                     (__attribute__((address_space(3))) void*)l, 16, 0, 0);
}

// -------- main: per-block 128 queries x 2048-point chunk; m97 K-loop inside --------
// grid = 128 mtiles x 8 chunks; bid = mtile*8 + chunk => chunk pins to one XCD L2.
__global__ __launch_bounds__(256, 3) void nn_mfma(const _Float16* __restrict__ A,   // [NQ][KTOT]
                                                  const _Float16* __restrict__ B,   // [N_PTS][KTOT]
                                                  const float* __restrict__ p_sq,
                                                  unsigned long long* __restrict__ keys) {
    __shared__ _Float16 As[BM * BK];   // 16 KB
    __shared__ _Float16 Bs[BN * BK];   // 16 KB

    const int bid   = blockIdx.x;
    const int mtile = bid >> 3;
    const int chunk = bid & 7;
    const int nbase = chunk * CHUNK_N;

    const int tid = threadIdx.x;
    const int w   = tid >> 6;           // wave 0..3
    const int l   = tid & 63;
    const int wq  = w >> 1;             // wave quadrant rows wq*64, cols wp*64
    const int wp  = w & 1;
    const int q16 = l >> 4;             // MFMA quad
    const int c16 = l & 15;

    const int srow = l >> 3;                    // staging row-in-8
    const int gch  = (l & 7) ^ ((l >> 3) & 7);  // swizzled global chunk for this lane
    const size_t arow0 = (size_t)mtile * BM;

    // running per-lane argmin state: 16 rows x (f32 best, u16 chunk-local idx)
    float    best[4][4];
    unsigned bpak[4][2];
#pragma unroll
    for (int mi = 0; mi < 4; ++mi) {
        best[mi][0] = best[mi][1] = best[mi][2] = best[mi][3] = 3.4e38f;
        bpak[mi][0] = bpak[mi][1] = 0;
    }

#pragma unroll 1
    for (int nt = 0; nt < CHUNK_NT; ++nt) {
        const size_t brow0 = (size_t)nbase + nt * BN;

        // prefetch p_sq for this ntile's 64 cols (per wave)
        float psq[4];
#pragma unroll
        for (int ni = 0; ni < 4; ++ni)
            psq[ni] = p_sq[brow0 + wp * 64 + ni * 16 + c16];

        f32x4 acc[4][4] = {};

        for (int kk = 0; kk < KTOT; kk += BK) {
            __syncthreads();
#pragma unroll
            for (int i = 0; i < 4; ++i) {
                int r = w * 32 + i * 8 + srow;
                gload16(A + (arow0 + r) * KTOT + kk + gch * 8, As + (size_t)(w * 32 + i * 8) * BK);
                gload16(B + (brow0 + r) * KTOT + kk + gch * 8, Bs + (size_t)(w * 32 + i * 8) * BK);
            }
            __syncthreads();

#pragma unroll
            for (int ks = 0; ks < 2; ++ks) {
                int ch = ks * 4 + q16;
                int slot = ch ^ (c16 & 7);
                half8 a[4], b[4];
#pragma unroll
                for (int mi = 0; mi < 4; ++mi)
                    a[mi] = *(const half8*)(As + (size_t)(wq * 64 + mi * 16 + c16) * BK + slot * 8);
#pragma unroll
                for (int ni = 0; ni < 4; ++ni)
                    b[ni] = *(const half8*)(Bs + (size_t)(wp * 64 + ni * 16 + c16) * BK + slot * 8);
#pragma unroll
                for (int mi = 0; mi < 4; ++mi)
#pragma unroll
                    for (int ni = 0; ni < 4; ++ni)
                        acc[mi][ni] = __builtin_amdgcn_mfma_f32_16x16x32_f16(a[mi], b[ni], acc[mi][ni], 0, 0, 0);
            }
        }

        // per-ntile state update (registers only; candidates ascend in idx => strict <)
#pragma unroll
        for (int mi = 0; mi < 4; ++mi)
#pragma unroll
            for (int reg = 0; reg < 4; ++reg) {
                float s0 = psq[0] - 2.0f * acc[mi][0][reg];
                float s1 = psq[1] - 2.0f * acc[mi][1][reg];
                float s2 = psq[2] - 2.0f * acc[mi][2][reg];
                float s3 = psq[3] - 2.0f * acc[mi][3][reg];
                float bv = s0; int bn = 0;
                if (s1 < bv) { bv = s1; bn = 1; }
                if (s2 < bv) { bv = s2; bn = 2; }
                if (s3 < bv) { bv = s3; bn = 3; }
                bool take = bv < best[mi][reg];
                unsigned lidx = (unsigned)(nt * BN + wp * 64 + (bn << 4) + c16); // < 2048
                unsigned sh = (reg & 1) * 16;
                unsigned cur = bpak[mi][reg >> 1];
                unsigned nw  = (cur & ~(0xFFFFu << sh)) | (lidx << sh);
                best[mi][reg]   = take ? bv : best[mi][reg];
                bpak[mi][reg >> 1] = take ? nw : cur;
            }
    }

    // final: butterfly across c16 lanes (per q16 group = one row), one atomic per row
#pragma unroll
    for (int mi = 0; mi < 4; ++mi)
#pragma unroll
        for (int reg = 0; reg < 4; ++reg) {
            float    bv   = best[mi][reg];
            unsigned lidx = (bpak[mi][reg >> 1] >> ((reg & 1) * 16)) & 0xFFFFu;
#pragma unroll
            for (int off = 1; off < 16; off <<= 1) {
                float    ov = __shfl_xor(bv, off, 64);
                unsigned oi = __shfl_xor((int)lidx, off, 64);
                if (ov < bv || (ov == bv && oi < lidx)) { bv = ov; lidx = oi; }
            }
            if (c16 == 0) {
                int row = mtile * BM + wq * 64 + mi * 16 + q16 * 4 + reg;
                unsigned long long key =
                    ((unsigned long long)f2sortable(bv) << 32) | (unsigned)(nbase + lidx);
                atomicMin(&keys[row], key);
            }
        }
}

// ---------------- gather: out[q] = values[key[q] & 0xffffffff] ----------------
__global__ __launch_bounds__(256) void gather_kernel(const unsigned long long* __restrict__ keys,
                                                     const float* __restrict__ values,
                                                     float* __restrict__ out) {
    int tid = threadIdx.x;
    int q = blockIdx.x * 16 + (tid >> 4);
    int c = tid & 15;
    int idx = (int)(keys[q] & 0xFFFFFFFFull);
    const float4* src = (const float4*)(values + (size_t)idx * NV);
    float4*       dst = (float4*)(out + (size_t)q * NV);
    dst[c] = src[c];
}

// ================= fallback (round-1 fp32 LDS kernel) =================
#define QT 64
#define PT 64
#define LSTRIDE 132
__global__ __launch_bounds__(256, 2) void nn_kernel(const float* __restrict__ points,
                                                    const float* __restrict__ values,
                                                    const float* __restrict__ pointsq,
                                                    const float* __restrict__ p_sq,
                                                    float* __restrict__ out) {
    __shared__ float lq[QT * LSTRIDE];
    __shared__ float lp[PT * LSTRIDE];
    __shared__ float lps[PT];
    __shared__ float red_val[QT][16];
    __shared__ int   red_idx[QT][16];
    __shared__ int   nn_idx[QT];

    const int tid = threadIdx.x;
    const int tx = tid & 15, ty = tid >> 4;
    const int qbase = blockIdx.x * QT;
    {
        int ql = tid >> 2, quad = tid & 3;
        const float4* src = (const float4*)(pointsq + (size_t)(qbase + ql) * DIMS);
#pragma unroll
        for (int j = 0; j < 8; ++j)
            *(float4*)(lq + ql * LSTRIDE + (quad + 4 * j) * 4) = src[quad + 4 * j];
    }
    float minv[4]; int mini[4];
#pragma unroll
    for (int qi = 0; qi < 4; ++qi) { minv[qi] = 3.4e38f; mini[qi] = 0; }
    for (int tile = 0; tile < N_PTS / PT; ++tile) {
        __syncthreads();
        {
            int pl = tid >> 2, quad = tid & 3;
            const float4* src = (const float4*)(points + (size_t)(tile * PT + pl) * DIMS);
#pragma unroll
            for (int j = 0; j < 8; ++j)
                *(float4*)(lp + pl * LSTRIDE + (quad + 4 * j) * 4) = src[quad + 4 * j];
            if (tid < PT) lps[tid] = p_sq[tile * PT + tid];
        }
        __syncthreads();
        float accl[4][4];
#pragma unroll
        for (int qi = 0; qi < 4; ++qi)
#pragma unroll
            for (int pi = 0; pi < 4; ++pi) accl[qi][pi] = 0.f;
        for (int kc = 0; kc < DIMS / 4; ++kc) {
            float4 aq[4], ap[4];
#pragma unroll
            for (int qi = 0; qi < 4; ++qi) aq[qi] = *(const float4*)(lq + (ty + 16 * qi) * LSTRIDE + kc * 4);
#pragma unroll
            for (int pi = 0; pi < 4; ++pi) ap[pi] = *(const float4*)(lp + (tx + 16 * pi) * LSTRIDE + kc * 4);
#pragma unroll
            for (int qi = 0; qi < 4; ++qi)
#pragma unroll
                for (int pi = 0; pi < 4; ++pi) {
                    accl[qi][pi] += aq[qi].x * ap[pi].x; accl[qi][pi] += aq[qi].y * ap[pi].y;
                    accl[qi][pi] += aq[qi].z * ap[pi].z; accl[qi][pi] += aq[qi].w * ap[pi].w;
                }
        }
#pragma unroll
        for (int qi = 0; qi < 4; ++qi)
#pragma unroll
            for (int pi = 0; pi < 4; ++pi) {
                float score = lps[tx + 16 * pi] - 2.f * accl[qi][pi];
                int idx = tile * PT + tx + 16 * pi;
                if (score < minv[qi]) { minv[qi] = score; mini[qi] = idx; }
            }
    }
    __syncthreads();
#pragma unroll
    for (int qi = 0; qi < 4; ++qi) { red_val[ty + 16 * qi][tx] = minv[qi]; red_idx[ty + 16 * qi][tx] = mini[qi]; }
    __syncthreads();
    if (tid < QT) {
        float bv = red_val[tid][0]; int bi = red_idx[tid][0];
#pragma unroll
        for (int t = 1; t < 16; ++t) {
            float v = red_val[tid][t]; int i = red_idx[tid][t];
            if (v < bv || (v == bv && i < bi)) { bv = v; bi = i; }
        }
        nn_idx[tid] = bi;
    }
    __syncthreads();
    {
        int ql = tid >> 2, quad = tid & 3;
        const float4* src = (const float4*)(values + (size_t)nn_idx[ql] * NV);
        float4* dst = (float4*)(out + (size_t)(qbase + ql) * NV);
#pragma unroll
        for (int j = 0; j < 4; ++j) dst[quad * 4 + j] = src[quad * 4 + j];
    }
}

__global__ __launch_bounds__(256) void psq_kernel(const float* __restrict__ points,
                                                  float* __restrict__ p_sq) {
    int row  = blockIdx.x * 4 + (threadIdx.x >> 6);
    int lane = threadIdx.x & 63;
    float2 v = *(const float2*)(points + row * DIMS + lane * 2);
    float s = v.x * v.x + v.y * v.y;
#pragma unroll
    for (int off = 32; off > 0; off >>= 1) s += __shfl_xor(s, off, 64);
    if (lane == 0) p_sq[row] = s;
}

extern "C" void kernel_launch(void* const* d_in, const int* in_sizes, int n_in,
                              void* d_out, int out_size, void* d_ws, size_t ws_size,
                              hipStream_t stream) {
    const float* points  = (const float*)d_in[0];
    const float* values  = (const float*)d_in[1];
    const float* pointsq = (const float*)d_in[2];
    float*       out     = (float*)d_out;

    // ws layout: keys (128 KB) | p_sq (64 KB) | A' (12 MB) | B' (12 MB)
    const size_t OFF_KEYS = 0;
    const size_t OFF_PSQ  = 131072;
    const size_t OFF_A    = 196608;
    const size_t OFF_B    = OFF_A + (size_t)NQ * KTOT * 2;
    const size_t NEEDED   = OFF_B + (size_t)N_PTS * KTOT * 2;

    if (ws_size >= NEEDED) {
        unsigned long long* keys = (unsigned long long*)((char*)d_ws + OFF_KEYS);
        float*    p_sq = (float*)((char*)d_ws + OFF_PSQ);
        _Float16* Aq   = (_Float16*)((char*)d_ws + OFF_A);
        _Float16* Bp   = (_Float16*)((char*)d_ws + OFF_B);

        hipMemsetAsync(keys, 0xFF, (size_t)NQ * 8, stream);
        split_q<<<NQ * DIMS / 1024, 256, 0, stream>>>(pointsq, Aq);
        split_p<<<N_PTS * DIMS / 1024, 256, 0, stream>>>(points, Bp, p_sq);
        nn_mfma<<<(NQ / BM) * NCHUNK, 256, 0, stream>>>(Aq, Bp, p_sq, keys);
        gather_kernel<<<NQ / 16, 256, 0, stream>>>(keys, values, out);
    } else {
        float* p_sq = (float*)d_ws;
        psq_kernel<<<N_PTS / 4, 256, 0, stream>>>(points, p_sq);
        nn_kernel<<<NQ / QT, 256, 0, stream>>>(points, values, pointsq, p_sq, out);
    }
}

// Round 6
// 344.919 us; speedup vs baseline: 1.7517x; 1.6599x over previous
//
#include <hip/hip_runtime.h>

#define N_PTS 16384
#define DIMS  128
#define NQ    16384
#define NV    64
#define KTOT  384   // 3 fp16 products: a1b1 + a1b2 + a2b1 (a2b2 dropped, ~3e-5 abs)
#define BK    64
#define BM    128
#define BN    128
#define NK6   (KTOT / BK)          // 6 kk-phases per ntile
#define CHUNK_NT 16                // ntiles per block
#define CHUNK_N  (BN * CHUNK_NT)   // 2048 points per block
#define NCHUNK   (N_PTS / CHUNK_N) // 8
#define NPHASE   (CHUNK_NT * NK6)  // 96

typedef __attribute__((ext_vector_type(8))) _Float16 half8;
typedef __attribute__((ext_vector_type(4))) _Float16 half4;
typedef __attribute__((ext_vector_type(4))) float    f32x4;

// ---------------- split queries: [h1 | h1 | h2] ----------------
__global__ __launch_bounds__(256) void split_q(const float* __restrict__ in,
                                               _Float16* __restrict__ out) {
    int t = blockIdx.x * 256 + threadIdx.x;
    int idx4 = t * 4;
    int r = idx4 >> 7, c = idx4 & 127;
    float4 x = *(const float4*)(in + idx4);
    float xs[4] = {x.x, x.y, x.z, x.w};
    half4 h1, h2;
#pragma unroll
    for (int j = 0; j < 4; ++j) {
        _Float16 a = (_Float16)xs[j];
        h1[j] = a;
        h2[j] = (_Float16)(xs[j] - (float)a);
    }
    _Float16* o = out + (size_t)r * KTOT + c;
    *(half4*)o = h1; *(half4*)(o + 128) = h1; *(half4*)(o + 256) = h2;
}

// ---------------- split points: [h1 | h2 | h1], fused p_sq ----------------
__global__ __launch_bounds__(256) void split_p(const float* __restrict__ in,
                                               _Float16* __restrict__ out,
                                               float* __restrict__ p_sq) {
    int t = blockIdx.x * 256 + threadIdx.x;
    int idx4 = t * 4;                 // 32 threads per 128-float row
    int r = idx4 >> 7, c = idx4 & 127;
    float4 x = *(const float4*)(in + idx4);
    float xs[4] = {x.x, x.y, x.z, x.w};
    half4 h1, h2;
    float s = 0.f;
#pragma unroll
    for (int j = 0; j < 4; ++j) {
        _Float16 a = (_Float16)xs[j];
        h1[j] = a;
        h2[j] = (_Float16)(xs[j] - (float)a);
        s += xs[j] * xs[j];
    }
    _Float16* o = out + (size_t)r * KTOT + c;
    *(half4*)o = h1; *(half4*)(o + 128) = h2; *(half4*)(o + 256) = h1;
#pragma unroll
    for (int off = 1; off < 32; off <<= 1) s += __shfl_xor(s, off, 64);
    if ((threadIdx.x & 31) == 0) p_sq[r] = s;
}

__device__ __forceinline__ unsigned int f2sortable(float f) {
    unsigned int b = __float_as_uint(f);
    return (b & 0x80000000u) ? ~b : (b | 0x80000000u);
}

__device__ __forceinline__ void gload16(const void* g, void* l) {
    __builtin_amdgcn_global_load_lds((const __attribute__((address_space(1))) void*)g,
                                     (__attribute__((address_space(3))) void*)l, 16, 0, 0);
}

// -------- main: 128 queries x 2048-pt chunk per block; single-barrier dbuf K-stream --------
// grid = 128 mtiles x 8 chunks; chunk = bid&7 => round-robin dispatch pins chunk B to one XCD L2.
__global__ __launch_bounds__(256, 2) void nn_mfma(const _Float16* __restrict__ A,   // [NQ][KTOT]
                                                  const _Float16* __restrict__ B,   // [N_PTS][KTOT]
                                                  const float* __restrict__ p_sq,
                                                  unsigned long long* __restrict__ keys) {
    __shared__ _Float16 As[2][BM * BK];   // 2 x 16 KB
    __shared__ _Float16 Bs[2][BN * BK];   // 2 x 16 KB

    const int bid   = blockIdx.x;
    const int mtile = bid >> 3;
    const int chunk = bid & 7;
    const int nbase = chunk * CHUNK_N;

    const int tid = threadIdx.x;
    const int w   = tid >> 6;           // wave 0..3
    const int l   = tid & 63;
    const int wq  = w >> 1;             // wave quadrant rows wq*64, cols wp*64
    const int wp  = w & 1;
    const int q16 = l >> 4;             // MFMA quad
    const int c16 = l & 15;

    const int srow = l >> 3;                    // staging row-in-8
    const int gch  = (l & 7) ^ ((l >> 3) & 7);  // swizzled global chunk for this lane
    const size_t arow0 = (size_t)mtile * BM;

    // stage one BK-slice of A and B into buffer `buf`
    auto stage = [&](int nt, int kk, int buf) {
        const size_t brow0 = (size_t)nbase + (size_t)nt * BN;
#pragma unroll
        for (int i = 0; i < 4; ++i) {
            int r = w * 32 + i * 8 + srow;
            gload16(A + (arow0 + r) * KTOT + kk + gch * 8, &As[buf][(size_t)(w * 32 + i * 8) * BK]);
            gload16(B + (brow0 + r) * KTOT + kk + gch * 8, &Bs[buf][(size_t)(w * 32 + i * 8) * BK]);
        }
    };

    // running per-lane argmin state: 16 rows x (f32 best, u16 chunk-local idx)
    float    best[4][4];
    unsigned bpak[4][2];
#pragma unroll
    for (int mi = 0; mi < 4; ++mi) {
        best[mi][0] = best[mi][1] = best[mi][2] = best[mi][3] = 3.4e38f;
        bpak[mi][0] = bpak[mi][1] = 0;
    }

    stage(0, 0, 0);   // prologue: fill buffer 0

#pragma unroll 1
    for (int nt = 0; nt < CHUNK_NT; ++nt) {
        const size_t brow0 = (size_t)nbase + (size_t)nt * BN;

        float psq[4];
#pragma unroll
        for (int ni = 0; ni < 4; ++ni)
            psq[ni] = p_sq[brow0 + wp * 64 + ni * 16 + c16];

        f32x4 acc[4][4] = {};

#pragma unroll 1
        for (int k6 = 0; k6 < NK6; ++k6) {
            const int p   = nt * NK6 + k6;
            const int buf = p & 1;

            __syncthreads();   // drains stage(p) (issued one compute-phase ago)

            // issue next stage into the other buffer BEFORE computing (async, in flight)
            if (p + 1 < NPHASE) {
                int ntn = (k6 == NK6 - 1) ? nt + 1 : nt;
                int kkn = (k6 == NK6 - 1) ? 0 : (k6 + 1) * BK;
                stage(ntn, kkn, buf ^ 1);
            }

            // compute on buf
#pragma unroll
            for (int ks = 0; ks < 2; ++ks) {
                int ch   = ks * 4 + q16;
                int slot = ch ^ (c16 & 7);
                half8 a[4], b[4];
#pragma unroll
                for (int mi = 0; mi < 4; ++mi)
                    a[mi] = *(const half8*)(&As[buf][(size_t)(wq * 64 + mi * 16 + c16) * BK + slot * 8]);
#pragma unroll
                for (int ni = 0; ni < 4; ++ni)
                    b[ni] = *(const half8*)(&Bs[buf][(size_t)(wp * 64 + ni * 16 + c16) * BK + slot * 8]);
#pragma unroll
                for (int mi = 0; mi < 4; ++mi)
#pragma unroll
                    for (int ni = 0; ni < 4; ++ni)
                        acc[mi][ni] = __builtin_amdgcn_mfma_f32_16x16x32_f16(a[mi], b[ni], acc[mi][ni], 0, 0, 0);
            }
        }

        // per-ntile state update (registers only; candidates ascend in idx => strict <)
#pragma unroll
        for (int mi = 0; mi < 4; ++mi)
#pragma unroll
            for (int reg = 0; reg < 4; ++reg) {
                float s0 = psq[0] - 2.0f * acc[mi][0][reg];
                float s1 = psq[1] - 2.0f * acc[mi][1][reg];
                float s2 = psq[2] - 2.0f * acc[mi][2][reg];
                float s3 = psq[3] - 2.0f * acc[mi][3][reg];
                float bv = s0; int bn = 0;
                if (s1 < bv) { bv = s1; bn = 1; }
                if (s2 < bv) { bv = s2; bn = 2; }
                if (s3 < bv) { bv = s3; bn = 3; }
                bool take = bv < best[mi][reg];
                unsigned lidx = (unsigned)(nt * BN + wp * 64 + (bn << 4) + c16); // < 2048
                unsigned sh = (reg & 1) * 16;
                unsigned cur = bpak[mi][reg >> 1];
                unsigned nw  = (cur & ~(0xFFFFu << sh)) | (lidx << sh);
                best[mi][reg]      = take ? bv : best[mi][reg];
                bpak[mi][reg >> 1] = take ? nw : cur;
            }
    }

    // final: butterfly across c16 lanes (per q16 group = one row), one atomic per row
#pragma unroll
    for (int mi = 0; mi < 4; ++mi)
#pragma unroll
        for (int reg = 0; reg < 4; ++reg) {
            float    bv   = best[mi][reg];
            unsigned lidx = (bpak[mi][reg >> 1] >> ((reg & 1) * 16)) & 0xFFFFu;
#pragma unroll
            for (int off = 1; off < 16; off <<= 1) {
                float    ov = __shfl_xor(bv, off, 64);
                unsigned oi = __shfl_xor((int)lidx, off, 64);
                if (ov < bv || (ov == bv && oi < lidx)) { bv = ov; lidx = oi; }
            }
            if (c16 == 0) {
                int row = mtile * BM + wq * 64 + mi * 16 + q16 * 4 + reg;
                unsigned long long key =
                    ((unsigned long long)f2sortable(bv) << 32) | (unsigned)(nbase + lidx);
                atomicMin(&keys[row], key);
            }
        }
}

// ---------------- gather: out[q] = values[key[q] & 0xffffffff] ----------------
__global__ __launch_bounds__(256) void gather_kernel(const unsigned long long* __restrict__ keys,
                                                     const float* __restrict__ values,
                                                     float* __restrict__ out) {
    int tid = threadIdx.x;
    int q = blockIdx.x * 16 + (tid >> 4);
    int c = tid & 15;
    int idx = (int)(keys[q] & 0xFFFFFFFFull);
    const float4* src = (const float4*)(values + (size_t)idx * NV);
    float4*       dst = (float4*)(out + (size_t)q * NV);
    dst[c] = src[c];
}

// ================= fallback (round-1 fp32 LDS kernel) =================
#define QT 64
#define PT 64
#define LSTRIDE 132
__global__ __launch_bounds__(256, 2) void nn_kernel(const float* __restrict__ points,
                                                    const float* __restrict__ values,
                                                    const float* __restrict__ pointsq,
                                                    const float* __restrict__ p_sq,
                                                    float* __restrict__ out) {
    __shared__ float lq[QT * LSTRIDE];
    __shared__ float lp[PT * LSTRIDE];
    __shared__ float lps[PT];
    __shared__ float red_val[QT][16];
    __shared__ int   red_idx[QT][16];
    __shared__ int   nn_idx[QT];

    const int tid = threadIdx.x;
    const int tx = tid & 15, ty = tid >> 4;
    const int qbase = blockIdx.x * QT;
    {
        int ql = tid >> 2, quad = tid & 3;
        const float4* src = (const float4*)(pointsq + (size_t)(qbase + ql) * DIMS);
#pragma unroll
        for (int j = 0; j < 8; ++j)
            *(float4*)(lq + ql * LSTRIDE + (quad + 4 * j) * 4) = src[quad + 4 * j];
    }
    float minv[4]; int mini[4];
#pragma unroll
    for (int qi = 0; qi < 4; ++qi) { minv[qi] = 3.4e38f; mini[qi] = 0; }
    for (int tile = 0; tile < N_PTS / PT; ++tile) {
        __syncthreads();
        {
            int pl = tid >> 2, quad = tid & 3;
            const float4* src = (const float4*)(points + (size_t)(tile * PT + pl) * DIMS);
#pragma unroll
            for (int j = 0; j < 8; ++j)
                *(float4*)(lp + pl * LSTRIDE + (quad + 4 * j) * 4) = src[quad + 4 * j];
            if (tid < PT) lps[tid] = p_sq[tile * PT + tid];
        }
        __syncthreads();
        float accl[4][4];
#pragma unroll
        for (int qi = 0; qi < 4; ++qi)
#pragma unroll
            for (int pi = 0; pi < 4; ++pi) accl[qi][pi] = 0.f;
        for (int kc = 0; kc < DIMS / 4; ++kc) {
            float4 aq[4], ap[4];
#pragma unroll
            for (int qi = 0; qi < 4; ++qi) aq[qi] = *(const float4*)(lq + (ty + 16 * qi) * LSTRIDE + kc * 4);
#pragma unroll
            for (int pi = 0; pi < 4; ++pi) ap[pi] = *(const float4*)(lp + (tx + 16 * pi) * LSTRIDE + kc * 4);
#pragma unroll
            for (int qi = 0; qi < 4; ++qi)
#pragma unroll
                for (int pi = 0; pi < 4; ++pi) {
                    accl[qi][pi] += aq[qi].x * ap[pi].x; accl[qi][pi] += aq[qi].y * ap[pi].y;
                    accl[qi][pi] += aq[qi].z * ap[pi].z; accl[qi][pi] += aq[qi].w * ap[pi].w;
                }
        }
#pragma unroll
        for (int qi = 0; qi < 4; ++qi)
#pragma unroll
            for (int pi = 0; pi < 4; ++pi) {
                float score = lps[tx + 16 * pi] - 2.f * accl[qi][pi];
                int idx = tile * PT + tx + 16 * pi;
                if (score < minv[qi]) { minv[qi] = score; mini[qi] = idx; }
            }
    }
    __syncthreads();
#pragma unroll
    for (int qi = 0; qi < 4; ++qi) { red_val[ty + 16 * qi][tx] = minv[qi]; red_idx[ty + 16 * qi][tx] = mini[qi]; }
    __syncthreads();
    if (tid < QT) {
        float bv = red_val[tid][0]; int bi = red_idx[tid][0];
#pragma unroll
        for (int t = 1; t < 16; ++t) {
            float v = red_val[tid][t]; int i = red_idx[tid][t];
            if (v < bv || (v == bv && i < bi)) { bv = v; bi = i; }
        }
        nn_idx[tid] = bi;
    }
    __syncthreads();
    {
        int ql = tid >> 2, quad = tid & 3;
        const float4* src = (const float4*)(values + (size_t)nn_idx[ql] * NV);
        float4* dst = (float4*)(out + (size_t)(qbase + ql) * NV);
#pragma unroll
        for (int j = 0; j < 4; ++j) dst[quad * 4 + j] = src[quad * 4 + j];
    }
}

__global__ __launch_bounds__(256) void psq_kernel(const float* __restrict__ points,
                                                  float* __restrict__ p_sq) {
    int row  = blockIdx.x * 4 + (threadIdx.x >> 6);
    int lane = threadIdx.x & 63;
    float2 v = *(const float2*)(points + row * DIMS + lane * 2);
    float s = v.x * v.x + v.y * v.y;
#pragma unroll
    for (int off = 32; off > 0; off >>= 1) s += __shfl_xor(s, off, 64);
    if (lane == 0) p_sq[row] = s;
}

extern "C" void kernel_launch(void* const* d_in, const int* in_sizes, int n_in,
                              void* d_out, int out_size, void* d_ws, size_t ws_size,
                              hipStream_t stream) {
    const float* points  = (const float*)d_in[0];
    const float* values  = (const float*)d_in[1];
    const float* pointsq = (const float*)d_in[2];
    float*       out     = (float*)d_out;

    // ws layout: keys (128 KB) | p_sq (64 KB) | A' (12 MB) | B' (12 MB)
    const size_t OFF_KEYS = 0;
    const size_t OFF_PSQ  = 131072;
    const size_t OFF_A    = 196608;
    const size_t OFF_B    = OFF_A + (size_t)NQ * KTOT * 2;
    const size_t NEEDED   = OFF_B + (size_t)N_PTS * KTOT * 2;

    if (ws_size >= NEEDED) {
        unsigned long long* keys = (unsigned long long*)((char*)d_ws + OFF_KEYS);
        float*    p_sq = (float*)((char*)d_ws + OFF_PSQ);
        _Float16* Aq   = (_Float16*)((char*)d_ws + OFF_A);
        _Float16* Bp   = (_Float16*)((char*)d_ws + OFF_B);

        hipMemsetAsync(keys, 0xFF, (size_t)NQ * 8, stream);
        split_q<<<NQ * DIMS / 1024, 256, 0, stream>>>(pointsq, Aq);
        split_p<<<N_PTS * DIMS / 1024, 256, 0, stream>>>(points, Bp, p_sq);
        nn_mfma<<<(NQ / BM) * NCHUNK, 256, 0, stream>>>(Aq, Bp, p_sq, keys);
        gather_kernel<<<NQ / 16, 256, 0, stream>>>(keys, values, out);
    } else {
        float* p_sq = (float*)d_ws;
        psq_kernel<<<N_PTS / 4, 256, 0, stream>>>(points, p_sq);
        nn_kernel<<<NQ / QT, 256, 0, stream>>>(points, values, pointsq, p_sq, out);
    }
}